// Round 3
// baseline (799.913 us; speedup 1.0000x reference)
//
#include <hip/hip_runtime.h>
#include <cstdint>
#include <cstddef>

typedef unsigned int  u32;
typedef unsigned short u16;
typedef _Float16 f16;
typedef _Float16 f16x2 __attribute__((ext_vector_type(2)));
typedef _Float16 half8 __attribute__((ext_vector_type(8)));
typedef float    f32x4v __attribute__((ext_vector_type(4)));
typedef int      i32x4 __attribute__((ext_vector_type(4)));

#define BATCH 64
#define TSEQ  512
#define DEMB  300
#define KPAD  320
#define HDIM  256
#define G4    1024
#define NCLS  9

__device__ __forceinline__ u32 packf16(float a, float b) {
  f16x2 v; v.x = (f16)a; v.y = (f16)b;
  return __builtin_bit_cast(u32, v);
}
__device__ __forceinline__ float f16f(u16 x) {
  return (float)__builtin_bit_cast(f16, x);
}
__device__ __forceinline__ float sigm_fast(float x) {
  return __builtin_amdgcn_rcpf(1.f + __expf(-x));
}
__device__ __forceinline__ float tanh_fast(float x) {
  float ax = __builtin_fabsf(x);
  float e = __expf(-2.f * ax);
  float t = (1.f - e) * __builtin_amdgcn_rcpf(1.f + e);
  return copysignf(t, x);
}
__device__ __forceinline__ int sdot4(int a, int b, int c) {
#if __has_builtin(__builtin_amdgcn_sdot4)
  return __builtin_amdgcn_sdot4(a, b, c, false);
#else
  int r;
  asm volatile("v_dot4_i32_i8 %0, %1, %2, %3" : "=v"(r) : "v"(a), "v"(b), "v"(c));
  return r;
#endif
}

// ---------------- P1: embf16[v][320] = f16(emb[v][0..299]), zero-pad 300..319 ----
__global__ __launch_bounds__(256) void embcvt_k(const float* __restrict__ emb,
                                                u16* __restrict__ out) {
  const int v  = blockIdx.x * 16 + (threadIdx.x >> 4);
  const int kc = threadIdx.x & 15;
  u32* __restrict__ dst = (u32*)(out + (size_t)v * KPAD + kc * 20);
  if (kc < 15) {
    const float* __restrict__ src = emb + (size_t)v * DEMB + kc * 20;
    float tmp[20];
#pragma unroll
    for (int j = 0; j < 20; ++j) tmp[j] = src[j];
#pragma unroll
    for (int j = 0; j < 10; ++j) dst[j] = packf16(tmp[2 * j], tmp[2 * j + 1]);
  } else {
#pragma unroll
    for (int j = 0; j < 10; ++j) dst[j] = 0u;
  }
}

// ---------------- P2: wkt[dir][col][320] = f16(Wk[k][col]), zero-pad k>=300 -----
__global__ __launch_bounds__(256) void wkt_k(const float* __restrict__ Wk_f,
                                             const float* __restrict__ Wk_b,
                                             u16* __restrict__ wkt) {
  const int dir = blockIdx.y;
  const float* __restrict__ Wk = dir ? Wk_b : Wk_f;
  const int col = blockIdx.x * 16 + (threadIdx.x >> 4);
  const int kc  = threadIdx.x & 15;
  u32* __restrict__ dst = (u32*)(wkt + ((size_t)dir * G4 + col) * KPAD + kc * 20);
  if (kc < 15) {
    float tmp[20];
#pragma unroll
    for (int j = 0; j < 20; ++j) tmp[j] = Wk[(size_t)(kc * 20 + j) * G4 + col];
#pragma unroll
    for (int j = 0; j < 10; ++j) dst[j] = packf16(tmp[2 * j], tmp[2 * j + 1]);
  } else {
#pragma unroll
    for (int j = 0; j < 10; ++j) dst[j] = 0u;
  }
}

// ---------------- P3: wr8[dir][col][256] = int8(Wr[k][col] * 512), k-major ----
__global__ __launch_bounds__(256) void wr8_k(const float* __restrict__ Wr_f,
                                             const float* __restrict__ Wr_b,
                                             signed char* __restrict__ wr8) {
  const int dir = blockIdx.y;
  const float* __restrict__ Wr = dir ? Wr_b : Wr_f;
  const int col = blockIdx.x * 16 + (threadIdx.x >> 4);
  const int k0  = (threadIdx.x & 15) * 16;
  float tmp[16];
#pragma unroll
  for (int j = 0; j < 16; ++j) tmp[j] = Wr[(size_t)(k0 + j) * G4 + col];
  u32 pw[4];
#pragma unroll
  for (int jj = 0; jj < 4; ++jj) {
    u32 p = 0;
#pragma unroll
    for (int b = 0; b < 4; ++b) {
      int q = (int)__builtin_rintf(tmp[4 * jj + b] * 512.f);
      q = q > 127 ? 127 : (q < -127 ? -127 : q);
      p |= ((u32)(q & 255)) << (8 * b);
    }
    pw[jj] = p;
  }
  *(uint4*)(wr8 + ((size_t)dir * G4 + col) * HDIM + k0) =
      make_uint4(pw[0], pw[1], pw[2], pw[3]);
}

// ---------------- K1: xz = emb[inputs] @ Wk + b  (MFMA f16) ----------------
__global__ __launch_bounds__(256) void xz_gemm_k(
    const int* __restrict__ inputs, const u16* __restrict__ wkt,
    const u16* __restrict__ embf16, const float* __restrict__ b_f,
    const float* __restrict__ b_b, u16* __restrict__ xz)
{
  __shared__ __align__(16) u16 As[128 * 40];   // [m][k], k-major, pad 32->40
  __shared__ __align__(16) u16 Bs[128 * 40];   // [n][k], k-major
  const int tid  = threadIdx.x;
  const int wv   = tid >> 6, lane = tid & 63;
  const int quad = lane >> 4, fl = lane & 15;
  const int cbi  = blockIdx.x;                 // 0..15
  const int dir  = cbi >> 3;
  const int cb1  = (cbi & 7) * 128;
  const int rb   = blockIdx.y * 128;
  const float* __restrict__ bias = dir ? b_b : b_f;

  const int sm = tid >> 1, sh = (tid & 1) * 16;          // staging row, k-half
  const int vrow = inputs[rb + sm];
  const u16* __restrict__ asrc = wkt + ((size_t)(dir * G4) + cb1 + sm) * KPAD + sh;
  const u16* __restrict__ bsrc = embf16 + (size_t)vrow * KPAD + sh;

  f32x4v acc[2][8];
#pragma unroll
  for (int bt = 0; bt < 2; ++bt)
#pragma unroll
    for (int i = 0; i < 8; ++i) acc[bt][i] = (f32x4v){0.f, 0.f, 0.f, 0.f};

  for (int kt = 0; kt < 10; ++kt) {
    const int k0 = kt * 32;
    uint4 a0v = *(const uint4*)(asrc + k0);
    uint4 a1v = *(const uint4*)(asrc + k0 + 8);
    uint4 b0v = *(const uint4*)(bsrc + k0);
    uint4 b1v = *(const uint4*)(bsrc + k0 + 8);
    *(uint4*)&As[sm * 40 + sh]     = a0v;
    *(uint4*)&As[sm * 40 + sh + 8] = a1v;
    *(uint4*)&Bs[sm * 40 + sh]     = b0v;
    *(uint4*)&Bs[sm * 40 + sh + 8] = b1v;
    __syncthreads();
    half8 bf[2];
#pragma unroll
    for (int bt = 0; bt < 2; ++bt)
      bf[bt] = *(const half8*)&Bs[(wv * 32 + bt * 16 + fl) * 40 + quad * 8];
#pragma unroll
    for (int i = 0; i < 8; ++i) {
      half8 af = *(const half8*)&As[(i * 16 + fl) * 40 + quad * 8];
      acc[0][i] = __builtin_amdgcn_mfma_f32_16x16x32_f16(af, bf[0], acc[0][i], 0, 0, 0);
      acc[1][i] = __builtin_amdgcn_mfma_f32_16x16x32_f16(af, bf[1], acc[1][i], 0, 0, 0);
    }
    __syncthreads();
  }
#pragma unroll
  for (int bt = 0; bt < 2; ++bt) {
    const int row = rb + wv * 32 + bt * 16 + fl;         // n = emb row
    u16* __restrict__ orow = xz + ((size_t)(dir * BATCH * TSEQ) + row) * G4;
#pragma unroll
    for (int i = 0; i < 8; ++i) {
      const int mb = cb1 + i * 16 + quad * 4;            // m = gate col
      const float4 bb = *(const float4*)&bias[mb];
      f32x4v v = acc[bt][i];
      uint2 pk;
      pk.x = packf16(v[0] + bb.x, v[1] + bb.y);
      pk.y = packf16(v[2] + bb.z, v[3] + bb.w);
      *(uint2*)&orow[mb] = pk;
    }
  }
}

// ---------------- K2: LSTM recurrence — v_dot4_i32_i8, zero M-redundancy ------
// Round-12: r11's VGPR_Count=84 proved the compiler rematerialized the 32
// weight loads inside the time loop (pin asm BEFORE the loop doesn't force
// liveness ACROSS it). Fix: no-op "+v" pin at the TOP of every iteration —
// remat would then need a reload before each pin, strictly worse, so regalloc
// must keep the 128 weight VGPRs resident. Also strength-reduced the per-step
// address math to pointer increments.
// Layout: thread pair owns h-index hidx=tid>>1. Even lane: gates i,g (cols
// hidx, 512+hidx); odd lane: f,o (cols 256+hidx, 768+hidx). shfl_xor(ig,1)
// (DPP quad_perm, no LDS) passes i*g to the odd lane holding (c,h).
// Per SIMD issue: 2 waves x 128 sdot4 x 2cy = 512 cy/step vs MFMA-map 1306.
#define PIN2(a, b) asm volatile("" : "+v"(a), "+v"(b))
__global__ __launch_bounds__(512, 2) void lstm_k(
    const u16* __restrict__ xz, const signed char* __restrict__ wr8,
    const int* __restrict__ lengths, u16* __restrict__ hcat)
{
  const int chain = blockIdx.x;
  const int dir   = chain >> 6;
  const int batch = chain & 63;
  const int tid   = threadIdx.x;
  const int odd   = tid & 1;
  const int hidx  = tid >> 1;                 // h-index 0..255
  const int c0    = odd * 256 + hidx;         // i (even) / f (odd)
  const int c1    = c0 + 512;                 // g (even) / o (odd)
  const float DEQ = 1.f / (512.f * 127.f);

  __shared__ __align__(16) signed char hpk[2][256];   // double-buffered h (i8)

  const signed char* __restrict__ wr8w = wr8 + (size_t)dir * G4 * HDIM;

  // pin both Wr columns: 2 x 64 dwords = 128 VGPRs
  i32x4 w0[16], w1[16];
#pragma unroll
  for (int j = 0; j < 16; ++j) {
    w0[j] = *(const i32x4*)(wr8w + (size_t)c0 * HDIM + j * 16);
    w1[j] = *(const i32x4*)(wr8w + (size_t)c1 * HDIM + j * 16);
  }

  if (tid < 256) hpk[0][tid] = 0;

  float c = 0.f, h = 0.f;                     // live on odd lanes
  const int len = lengths[batch];
  const u16* __restrict__ xzb = xz + (size_t)(dir * BATCH + batch) * TSEQ * G4;
  u16* __restrict__ hrow = hcat + (size_t)batch * TSEQ * 512 + dir * 256;
  __syncthreads();

  int tt = dir ? (TSEQ - 1) : 0;
  const int dt = dir ? -1 : 1;
  const long xstride = (long)dt * G4;
  const long hstride = (long)dt * 512;
  const u16* xp = xzb + (size_t)tt * G4;
  u16* hp = hrow + (size_t)tt * 512;
  u16 x0 = xp[c0];
  u16 x1 = xp[c1];

  for (int st = 0; st < TSEQ; ++st) {
    // --- force weight residency: remat before this pin would cost more ---
#pragma unroll
    for (int j = 0; j < 16; j += 2) {
      PIN2(w0[j], w0[j + 1]);
      PIN2(w1[j], w1[j + 1]);
    }
    const u16* xpn = (st == TSEQ - 1) ? xp : (xp + xstride);
    u16 xn0 = xpn[c0];                        // prefetch next step's xz
    u16 xn1 = xpn[c1];

    const int par = st & 1;
    const signed char* hb = &hpk[par][0];

    int a0p = 0, a0q = 0, a1p = 0, a1q = 0;   // 4 independent dep chains
#pragma unroll
    for (int ch = 0; ch < 4; ++ch) {
      i32x4 hv[4];
#pragma unroll
      for (int q = 0; q < 4; ++q)
        hv[q] = *(const i32x4*)(hb + ch * 64 + q * 16);   // broadcast read
#pragma unroll
      for (int q = 0; q < 4; ++q) {
#pragma unroll
        for (int e = 0; e < 4; ++e) {
          if (((q * 4 + e) & 1) == 0) {
            a0p = sdot4(hv[q][e], w0[ch * 4 + q][e], a0p);
            a1p = sdot4(hv[q][e], w1[ch * 4 + q][e], a1p);
          } else {
            a0q = sdot4(hv[q][e], w0[ch * 4 + q][e], a0q);
            a1q = sdot4(hv[q][e], w1[ch * 4 + q][e], a1q);
          }
        }
      }
    }
    const int s0 = a0p + a0q;
    const int s1 = a1p + a1q;

    float z0 = (float)s0 * DEQ + f16f(x0);    // zi (even) / zf (odd)
    float z1 = (float)s1 * DEQ + f16f(x1);    // zg (even) / zo (odd)
    float g0 = sigm_fast(z0);                 // i (even) / f (odd)
    // g1: tanh(zg) on even, sigm(zo) on odd — one exp either way
    float earg = odd ? -z1 : (-2.f * __builtin_fabsf(z1));
    float e = __expf(earg);
    float d = __builtin_amdgcn_rcpf(1.f + e);
    float g1 = odd ? d : copysignf((1.f - e) * d, z1);

    float P = g0 * g1;                        // even: i*g (odd lane ignores)
    float Pin = __shfl_xor(P, 1);             // odd receives i*g (DPP)
    if (odd) {
      float cn = fmaf(g0, c, Pin);            // f*c + i*g
      float hn = g1 * tanh_fast(cn);          // o * tanh(c)
      if (tt < len) { c = cn; h = hn; }       // masked step: hold state
      u32 hb2 = packf16(h, h);
      hp[hidx] = (u16)(hb2 & 0xffffu);
      int hq = (int)__builtin_rintf(h * 127.f);
      hpk[par ^ 1][hidx] = (signed char)hq;
    }
    __syncthreads();
    x0 = xn0; x1 = xn1; tt += dt;
    xp = xpn;
    if (st != TSEQ - 1) hp += hstride;
  }
}

// ---------------- K3: logits = hcat @ dense_W + dense_b ----------------
__global__ __launch_bounds__(256) void dense_k(
    const u16* __restrict__ hcat, const float* __restrict__ W,
    const float* __restrict__ bias, float* __restrict__ out)
{
  const int lane = threadIdx.x & 63;
  const int wv = threadIdx.x >> 6;
  const int rowbase = (blockIdx.x * 4 + wv) * 8;
  for (int rr = 0; rr < 8; ++rr) {
    const int row = rowbase + rr;
    const u16* __restrict__ hr = hcat + (size_t)row * 512;
    float hv[8];
#pragma unroll
    for (int i = 0; i < 8; ++i)
      hv[i] = f16f(hr[i * 64 + lane]);
    float myout = 0.f;
#pragma unroll
    for (int cc = 0; cc < 9; ++cc) {
      float p = 0.f;
#pragma unroll
      for (int i = 0; i < 8; ++i)
        p = fmaf(hv[i], W[(size_t)(i * 64 + lane) * 9 + cc], p);
#pragma unroll
      for (int o = 32; o > 0; o >>= 1) p += __shfl_xor(p, o);
      if (lane == cc) myout = p + bias[cc];
    }
    if (lane < 9) out[(size_t)row * 9 + lane] = myout;
  }
}

// ---------------- K4: CRF log-likelihood + trans copy ----------------
__global__ __launch_bounds__(64) void crf_k(
    const float* __restrict__ logits, const int* __restrict__ tags,
    const int* __restrict__ lengths, const float* __restrict__ trans,
    float* __restrict__ out_ll, float* __restrict__ out_trans)
{
  const int b = blockIdx.x;
  const int lane = threadIdx.x;
  const int len = lengths[b];
  const float* __restrict__ lg = logits + (size_t)b * TSEQ * NCLS;
  const int* __restrict__ tg = tags + (size_t)b * TSEQ;

  float ua = 0.f, ba = 0.f;
  for (int t = lane; t < TSEQ; t += 64) {
    int tag = tg[t];
    if (t < len) ua += lg[t * 9 + tag];
    if (t < len - 1) ba += trans[tag * 9 + tg[t + 1]];
  }
  float s = ua + ba;
#pragma unroll
  for (int o = 32; o > 0; o >>= 1) s += __shfl_xor(s, o);

  const int j = (lane < 9) ? lane : 0;
  float trc[9], alpha[9];
#pragma unroll
  for (int i = 0; i < 9; ++i) trc[i] = trans[i * 9 + j];
#pragma unroll
  for (int i = 0; i < 9; ++i) alpha[i] = lg[i];
  for (int t = 1; t < TSEQ; ++t) {
    if (t >= len) break;                 // mask is monotone
    float m = -1e30f;
#pragma unroll
    for (int i = 0; i < 9; ++i) m = fmaxf(m, alpha[i] + trc[i]);
    float ss = 0.f;
#pragma unroll
    for (int i = 0; i < 9; ++i) ss += __expf(alpha[i] + trc[i] - m);
    float nj = __logf(ss) + m + lg[t * 9 + j];
#pragma unroll
    for (int i = 0; i < 9; ++i) alpha[i] = __shfl(nj, i);
  }
  float m2 = -1e30f;
#pragma unroll
  for (int i = 0; i < 9; ++i) m2 = fmaxf(m2, alpha[i]);
  float s2 = 0.f;
#pragma unroll
  for (int i = 0; i < 9; ++i) s2 += __expf(alpha[i] - m2);
  float lse = __logf(s2) + m2;
  if (lane == 0) out_ll[b] = s - lse;
  if (b == 0)
    for (int i = lane; i < 81; i += 64) out_trans[i] = trans[i];
}

// ---------------- launch ----------------
extern "C" void kernel_launch(void* const* d_in, const int* in_sizes, int n_in,
                              void* d_out, int out_size, void* d_ws, size_t ws_size,
                              hipStream_t stream)
{
  const int*   inputs  = (const int*)d_in[0];
  const int*   lengths = (const int*)d_in[1];
  const int*   targets = (const int*)d_in[2];
  const float* emb     = (const float*)d_in[3];
  const float* Wk_f    = (const float*)d_in[4];
  const float* Wr_f    = (const float*)d_in[5];
  const float* b_f     = (const float*)d_in[6];
  const float* Wk_b    = (const float*)d_in[7];
  const float* Wr_b    = (const float*)d_in[8];
  const float* b_b     = (const float*)d_in[9];
  const float* dense_W = (const float*)d_in[10];
  const float* dense_b = (const float*)d_in[11];
  const float* trans   = (const float*)d_in[12];

  char* ws = (char*)d_ws;
  u16*         wkt    = (u16*)ws;                              //  1,310,720 B
  signed char* wr8    = (signed char*)(ws + 1310720ull);       //    524,288 B
  u16*         embf16 = (u16*)(ws + 1835008ull);               // 19,200,000 B
  u16*         xz     = (u16*)(ws + 1835008ull + 19200000ull); // 134,217,728 B
  u16*         hcat   = (u16*)(ws + 1835008ull + 19200000ull + 134217728ull); // 33,554,432 B

  float* out_logits = (float*)d_out;
  float* out_ll     = out_logits + (size_t)BATCH * TSEQ * NCLS;
  float* out_trans  = out_ll + BATCH;

  hipLaunchKernelGGL(embcvt_k, dim3(1875), dim3(256), 0, stream, emb, embf16);
  hipLaunchKernelGGL(wkt_k, dim3(64, 2), dim3(256), 0, stream, Wk_f, Wk_b, wkt);
  hipLaunchKernelGGL(wr8_k, dim3(64, 2), dim3(256), 0, stream, Wr_f, Wr_b, wr8);
  hipLaunchKernelGGL(xz_gemm_k, dim3(16, 256), dim3(256), 0, stream,
                     inputs, wkt, embf16, b_f, b_b, xz);
  hipLaunchKernelGGL(lstm_k, dim3(128), dim3(512), 0, stream,
                     xz, wr8, lengths, hcat);
  hipLaunchKernelGGL(dense_k, dim3(1024), dim3(256), 0, stream,
                     hcat, dense_W, dense_b, out_logits);
  hipLaunchKernelGGL(crf_k, dim3(64), dim3(64), 0, stream,
                     out_logits, targets, lengths, trans, out_ll, out_trans);
}

// Round 4
// 785.441 us; speedup vs baseline: 1.0184x; 1.0184x over previous
//
#include <hip/hip_runtime.h>
#include <cstdint>
#include <cstddef>

typedef unsigned int  u32;
typedef unsigned short u16;
typedef _Float16 f16;
typedef _Float16 f16x2 __attribute__((ext_vector_type(2)));
typedef _Float16 half8 __attribute__((ext_vector_type(8)));
typedef float    f32x4v __attribute__((ext_vector_type(4)));
typedef int      i32x4 __attribute__((ext_vector_type(4)));

#define BATCH 64
#define TSEQ  512
#define DEMB  300
#define KPAD  320
#define HDIM  256
#define G4    1024
#define NCLS  9

__device__ __forceinline__ u32 packf16(float a, float b) {
  f16x2 v; v.x = (f16)a; v.y = (f16)b;
  return __builtin_bit_cast(u32, v);
}
__device__ __forceinline__ float f16f(u16 x) {
  return (float)__builtin_bit_cast(f16, x);
}
__device__ __forceinline__ float sigm_fast(float x) {
  return __builtin_amdgcn_rcpf(1.f + __expf(-x));
}
__device__ __forceinline__ float tanh_fast(float x) {
  float ax = __builtin_fabsf(x);
  float e = __expf(-2.f * ax);
  float t = (1.f - e) * __builtin_amdgcn_rcpf(1.f + e);
  return copysignf(t, x);
}
__device__ __forceinline__ int sdot4(int a, int b, int c) {
#if __has_builtin(__builtin_amdgcn_sdot4)
  return __builtin_amdgcn_sdot4(a, b, c, false);
#else
  int r;
  asm volatile("v_dot4_i32_i8 %0, %1, %2, %3" : "=v"(r) : "v"(a), "v"(b), "v"(c));
  return r;
#endif
}

// ---------------- P1: embf16[v][320] = f16(emb[v][0..299]), zero-pad 300..319 ----
__global__ __launch_bounds__(256) void embcvt_k(const float* __restrict__ emb,
                                                u16* __restrict__ out) {
  const int v  = blockIdx.x * 16 + (threadIdx.x >> 4);
  const int kc = threadIdx.x & 15;
  u32* __restrict__ dst = (u32*)(out + (size_t)v * KPAD + kc * 20);
  if (kc < 15) {
    const float* __restrict__ src = emb + (size_t)v * DEMB + kc * 20;
    float tmp[20];
#pragma unroll
    for (int j = 0; j < 20; ++j) tmp[j] = src[j];
#pragma unroll
    for (int j = 0; j < 10; ++j) dst[j] = packf16(tmp[2 * j], tmp[2 * j + 1]);
  } else {
#pragma unroll
    for (int j = 0; j < 10; ++j) dst[j] = 0u;
  }
}

// ---------------- P2: wkt[dir][col][320] = f16(Wk[k][col]), zero-pad k>=300 -----
__global__ __launch_bounds__(256) void wkt_k(const float* __restrict__ Wk_f,
                                             const float* __restrict__ Wk_b,
                                             u16* __restrict__ wkt) {
  const int dir = blockIdx.y;
  const float* __restrict__ Wk = dir ? Wk_b : Wk_f;
  const int col = blockIdx.x * 16 + (threadIdx.x >> 4);
  const int kc  = threadIdx.x & 15;
  u32* __restrict__ dst = (u32*)(wkt + ((size_t)dir * G4 + col) * KPAD + kc * 20);
  if (kc < 15) {
    float tmp[20];
#pragma unroll
    for (int j = 0; j < 20; ++j) tmp[j] = Wk[(size_t)(kc * 20 + j) * G4 + col];
#pragma unroll
    for (int j = 0; j < 10; ++j) dst[j] = packf16(tmp[2 * j], tmp[2 * j + 1]);
  } else {
#pragma unroll
    for (int j = 0; j < 10; ++j) dst[j] = 0u;
  }
}

// ---------------- P3: wr8[dir][col][256] = int8(Wr[k][col] * 512), k-major ----
__global__ __launch_bounds__(256) void wr8_k(const float* __restrict__ Wr_f,
                                             const float* __restrict__ Wr_b,
                                             signed char* __restrict__ wr8) {
  const int dir = blockIdx.y;
  const float* __restrict__ Wr = dir ? Wr_b : Wr_f;
  const int col = blockIdx.x * 16 + (threadIdx.x >> 4);
  const int k0  = (threadIdx.x & 15) * 16;
  float tmp[16];
#pragma unroll
  for (int j = 0; j < 16; ++j) tmp[j] = Wr[(size_t)(k0 + j) * G4 + col];
  u32 pw[4];
#pragma unroll
  for (int jj = 0; jj < 4; ++jj) {
    u32 p = 0;
#pragma unroll
    for (int b = 0; b < 4; ++b) {
      int q = (int)__builtin_rintf(tmp[4 * jj + b] * 512.f);
      q = q > 127 ? 127 : (q < -127 ? -127 : q);
      p |= ((u32)(q & 255)) << (8 * b);
    }
    pw[jj] = p;
  }
  *(uint4*)(wr8 + ((size_t)dir * G4 + col) * HDIM + k0) =
      make_uint4(pw[0], pw[1], pw[2], pw[3]);
}

// ---------------- K1: xz = emb[inputs] @ Wk + b  (MFMA f16) ----------------
__global__ __launch_bounds__(256) void xz_gemm_k(
    const int* __restrict__ inputs, const u16* __restrict__ wkt,
    const u16* __restrict__ embf16, const float* __restrict__ b_f,
    const float* __restrict__ b_b, u16* __restrict__ xz)
{
  __shared__ __align__(16) u16 As[128 * 40];   // [m][k], k-major, pad 32->40
  __shared__ __align__(16) u16 Bs[128 * 40];   // [n][k], k-major
  const int tid  = threadIdx.x;
  const int wv   = tid >> 6, lane = tid & 63;
  const int quad = lane >> 4, fl = lane & 15;
  const int cbi  = blockIdx.x;                 // 0..15
  const int dir  = cbi >> 3;
  const int cb1  = (cbi & 7) * 128;
  const int rb   = blockIdx.y * 128;
  const float* __restrict__ bias = dir ? b_b : b_f;

  const int sm = tid >> 1, sh = (tid & 1) * 16;          // staging row, k-half
  const int vrow = inputs[rb + sm];
  const u16* __restrict__ asrc = wkt + ((size_t)(dir * G4) + cb1 + sm) * KPAD + sh;
  const u16* __restrict__ bsrc = embf16 + (size_t)vrow * KPAD + sh;

  f32x4v acc[2][8];
#pragma unroll
  for (int bt = 0; bt < 2; ++bt)
#pragma unroll
    for (int i = 0; i < 8; ++i) acc[bt][i] = (f32x4v){0.f, 0.f, 0.f, 0.f};

  for (int kt = 0; kt < 10; ++kt) {
    const int k0 = kt * 32;
    uint4 a0v = *(const uint4*)(asrc + k0);
    uint4 a1v = *(const uint4*)(asrc + k0 + 8);
    uint4 b0v = *(const uint4*)(bsrc + k0);
    uint4 b1v = *(const uint4*)(bsrc + k0 + 8);
    *(uint4*)&As[sm * 40 + sh]     = a0v;
    *(uint4*)&As[sm * 40 + sh + 8] = a1v;
    *(uint4*)&Bs[sm * 40 + sh]     = b0v;
    *(uint4*)&Bs[sm * 40 + sh + 8] = b1v;
    __syncthreads();
    half8 bf[2];
#pragma unroll
    for (int bt = 0; bt < 2; ++bt)
      bf[bt] = *(const half8*)&Bs[(wv * 32 + bt * 16 + fl) * 40 + quad * 8];
#pragma unroll
    for (int i = 0; i < 8; ++i) {
      half8 af = *(const half8*)&As[(i * 16 + fl) * 40 + quad * 8];
      acc[0][i] = __builtin_amdgcn_mfma_f32_16x16x32_f16(af, bf[0], acc[0][i], 0, 0, 0);
      acc[1][i] = __builtin_amdgcn_mfma_f32_16x16x32_f16(af, bf[1], acc[1][i], 0, 0, 0);
    }
    __syncthreads();
  }
#pragma unroll
  for (int bt = 0; bt < 2; ++bt) {
    const int row = rb + wv * 32 + bt * 16 + fl;         // n = emb row
    u16* __restrict__ orow = xz + ((size_t)(dir * BATCH * TSEQ) + row) * G4;
#pragma unroll
    for (int i = 0; i < 8; ++i) {
      const int mb = cb1 + i * 16 + quad * 4;            // m = gate col
      const float4 bb = *(const float4*)&bias[mb];
      f32x4v v = acc[bt][i];
      uint2 pk;
      pk.x = packf16(v[0] + bb.x, v[1] + bb.y);
      pk.y = packf16(v[2] + bb.z, v[3] + bb.w);
      *(uint2*)&orow[mb] = pk;
    }
  }
}

// ---------------- K2: LSTM recurrence — v_dot4_i32_i8, zero M-redundancy ------
// Round-13: r11/r12's VGPR_Count=84 with identical codegen proved the "+v"
// pins were satisfied by REMATERIALIZATION — the compiler re-emits the
// (restrict-const, provably-invariant) weight loads before each pin instead
// of keeping them resident. Fix: load the weights VIA inline asm. An
// INLINEASM def can never be rematerialized, so the allocator must keep the
// 128 weight dwords in VGPRs (pressure ~185 < 256-reg cap at 2 waves/SIMD)
// or spill to scratch (loudly visible). Rule-18 hazard handled: explicit
// s_waitcnt vmcnt(0) + sched_barrier(0) + "+v" pins AFTER the wait — sdot4
// consumers data-depend on pin outputs so they cannot hoist above the wait.
// Layout: thread pair owns h-index hidx=tid>>1. Even lane: gates i,g (cols
// hidx, 512+hidx); odd lane: f,o (cols 256+hidx, 768+hidx). shfl_xor(ig,1)
// passes i*g to the odd lane holding (c,h) state.
// Per SIMD issue: 2 waves x 128 sdot4 x 2cy = 512 cy/step vs MFMA-map 1306.
#define WLD(dst, p, off) \
  asm volatile("global_load_dwordx4 %0, %1, off offset:" #off \
               : "=v"(dst) : "v"(p));
#define WLDALL(w, p) \
  WLD(w[0], p, 0)    WLD(w[1], p, 16)   WLD(w[2], p, 32)   WLD(w[3], p, 48) \
  WLD(w[4], p, 64)   WLD(w[5], p, 80)   WLD(w[6], p, 96)   WLD(w[7], p, 112) \
  WLD(w[8], p, 128)  WLD(w[9], p, 144)  WLD(w[10], p, 160) WLD(w[11], p, 176) \
  WLD(w[12], p, 192) WLD(w[13], p, 208) WLD(w[14], p, 224) WLD(w[15], p, 240)

__global__ __launch_bounds__(512, 2) void lstm_k(
    const u16* __restrict__ xz, const signed char* __restrict__ wr8,
    const int* __restrict__ lengths, u16* __restrict__ hcat)
{
  const int chain = blockIdx.x;
  const int dir   = chain >> 6;
  const int batch = chain & 63;
  const int tid   = threadIdx.x;
  const int odd   = tid & 1;
  const int hidx  = tid >> 1;                 // h-index 0..255
  const int c0    = odd * 256 + hidx;         // i (even) / f (odd)
  const int c1    = c0 + 512;                 // g (even) / o (odd)
  const float DEQ = 1.f / (512.f * 127.f);

  __shared__ __align__(16) signed char hpk[2][256];   // double-buffered h (i8)

  const signed char* __restrict__ wr8w = wr8 + (size_t)dir * G4 * HDIM;

  // pin both Wr columns: 2 x 64 dwords = 128 VGPRs, loaded via inline asm
  // (non-rematerializable defs -> must stay resident)
  i32x4 w0[16], w1[16];
  {
    const signed char* p0 = wr8w + (size_t)c0 * HDIM;
    const signed char* p1 = wr8w + (size_t)c1 * HDIM;
    WLDALL(w0, p0)
    WLDALL(w1, p1)
  }
  asm volatile("s_waitcnt vmcnt(0)");
  __builtin_amdgcn_sched_barrier(0);
#pragma unroll
  for (int j = 0; j < 16; ++j) {
    asm volatile("" : "+v"(w0[j]));
    asm volatile("" : "+v"(w1[j]));
  }

  if (tid < 256) hpk[0][tid] = 0;

  float c = 0.f, h = 0.f;                     // live on odd lanes
  const int len = lengths[batch];
  const u16* __restrict__ xzb = xz + (size_t)(dir * BATCH + batch) * TSEQ * G4;
  u16* __restrict__ hrow = hcat + (size_t)batch * TSEQ * 512 + dir * 256;
  __syncthreads();

  int tt = dir ? (TSEQ - 1) : 0;
  const int dt = dir ? -1 : 1;
  const long xstride = (long)dt * G4;
  const long hstride = (long)dt * 512;
  const u16* xp = xzb + (size_t)tt * G4;
  u16* hp = hrow + (size_t)tt * 512;
  u16 x0 = xp[c0];
  u16 x1 = xp[c1];

  for (int st = 0; st < TSEQ; ++st) {
    const u16* xpn = (st == TSEQ - 1) ? xp : (xp + xstride);
    u16 xn0 = xpn[c0];                        // prefetch next step's xz
    u16 xn1 = xpn[c1];

    const int par = st & 1;
    const signed char* hb = &hpk[par][0];

    int a0p = 0, a0q = 0, a1p = 0, a1q = 0;   // 4 independent dep chains
#pragma unroll
    for (int ch = 0; ch < 4; ++ch) {
      i32x4 hv[4];
#pragma unroll
      for (int q = 0; q < 4; ++q)
        hv[q] = *(const i32x4*)(hb + ch * 64 + q * 16);   // broadcast read
#pragma unroll
      for (int q = 0; q < 4; ++q) {
#pragma unroll
        for (int e = 0; e < 4; ++e) {
          if (((q * 4 + e) & 1) == 0) {
            a0p = sdot4(hv[q][e], w0[ch * 4 + q][e], a0p);
            a1p = sdot4(hv[q][e], w1[ch * 4 + q][e], a1p);
          } else {
            a0q = sdot4(hv[q][e], w0[ch * 4 + q][e], a0q);
            a1q = sdot4(hv[q][e], w1[ch * 4 + q][e], a1q);
          }
        }
      }
    }
    const int s0 = a0p + a0q;
    const int s1 = a1p + a1q;

    float z0 = (float)s0 * DEQ + f16f(x0);    // zi (even) / zf (odd)
    float z1 = (float)s1 * DEQ + f16f(x1);    // zg (even) / zo (odd)
    float g0 = sigm_fast(z0);                 // i (even) / f (odd)
    // g1: tanh(zg) on even, sigm(zo) on odd — one exp either way
    float earg = odd ? -z1 : (-2.f * __builtin_fabsf(z1));
    float e = __expf(earg);
    float d = __builtin_amdgcn_rcpf(1.f + e);
    float g1 = odd ? d : copysignf((1.f - e) * d, z1);

    float P = g0 * g1;                        // even: i*g (odd lane ignores)
    float Pin = __shfl_xor(P, 1);             // odd receives i*g
    if (odd) {
      float cn = fmaf(g0, c, Pin);            // f*c + i*g
      float hn = g1 * tanh_fast(cn);          // o * tanh(c)
      if (tt < len) { c = cn; h = hn; }       // masked step: hold state
      u32 hb2 = packf16(h, h);
      hp[hidx] = (u16)(hb2 & 0xffffu);
      int hq = (int)__builtin_rintf(h * 127.f);
      hpk[par ^ 1][hidx] = (signed char)hq;
    }
    __syncthreads();
    x0 = xn0; x1 = xn1; tt += dt;
    xp = xpn;
    if (st != TSEQ - 1) hp += hstride;
  }
}

// ---------------- K3: logits = hcat @ dense_W + dense_b ----------------
__global__ __launch_bounds__(256) void dense_k(
    const u16* __restrict__ hcat, const float* __restrict__ W,
    const float* __restrict__ bias, float* __restrict__ out)
{
  const int lane = threadIdx.x & 63;
  const int wv = threadIdx.x >> 6;
  const int rowbase = (blockIdx.x * 4 + wv) * 8;
  for (int rr = 0; rr < 8; ++rr) {
    const int row = rowbase + rr;
    const u16* __restrict__ hr = hcat + (size_t)row * 512;
    float hv[8];
#pragma unroll
    for (int i = 0; i < 8; ++i)
      hv[i] = f16f(hr[i * 64 + lane]);
    float myout = 0.f;
#pragma unroll
    for (int cc = 0; cc < 9; ++cc) {
      float p = 0.f;
#pragma unroll
      for (int i = 0; i < 8; ++i)
        p = fmaf(hv[i], W[(size_t)(i * 64 + lane) * 9 + cc], p);
#pragma unroll
      for (int o = 32; o > 0; o >>= 1) p += __shfl_xor(p, o);
      if (lane == cc) myout = p + bias[cc];
    }
    if (lane < 9) out[(size_t)row * 9 + lane] = myout;
  }
}

// ---------------- K4: CRF log-likelihood + trans copy ----------------
__global__ __launch_bounds__(64) void crf_k(
    const float* __restrict__ logits, const int* __restrict__ tags,
    const int* __restrict__ lengths, const float* __restrict__ trans,
    float* __restrict__ out_ll, float* __restrict__ out_trans)
{
  const int b = blockIdx.x;
  const int lane = threadIdx.x;
  const int len = lengths[b];
  const float* __restrict__ lg = logits + (size_t)b * TSEQ * NCLS;
  const int* __restrict__ tg = tags + (size_t)b * TSEQ;

  float ua = 0.f, ba = 0.f;
  for (int t = lane; t < TSEQ; t += 64) {
    int tag = tg[t];
    if (t < len) ua += lg[t * 9 + tag];
    if (t < len - 1) ba += trans[tag * 9 + tg[t + 1]];
  }
  float s = ua + ba;
#pragma unroll
  for (int o = 32; o > 0; o >>= 1) s += __shfl_xor(s, o);

  const int j = (lane < 9) ? lane : 0;
  float trc[9], alpha[9];
#pragma unroll
  for (int i = 0; i < 9; ++i) trc[i] = trans[i * 9 + j];
#pragma unroll
  for (int i = 0; i < 9; ++i) alpha[i] = lg[i];
  for (int t = 1; t < TSEQ; ++t) {
    if (t >= len) break;                 // mask is monotone
    float m = -1e30f;
#pragma unroll
    for (int i = 0; i < 9; ++i) m = fmaxf(m, alpha[i] + trc[i]);
    float ss = 0.f;
#pragma unroll
    for (int i = 0; i < 9; ++i) ss += __expf(alpha[i] + trc[i] - m);
    float nj = __logf(ss) + m + lg[t * 9 + j];
#pragma unroll
    for (int i = 0; i < 9; ++i) alpha[i] = __shfl(nj, i);
  }
  float m2 = -1e30f;
#pragma unroll
  for (int i = 0; i < 9; ++i) m2 = fmaxf(m2, alpha[i]);
  float s2 = 0.f;
#pragma unroll
  for (int i = 0; i < 9; ++i) s2 += __expf(alpha[i] - m2);
  float lse = __logf(s2) + m2;
  if (lane == 0) out_ll[b] = s - lse;
  if (b == 0)
    for (int i = lane; i < 81; i += 64) out_trans[i] = trans[i];
}

// ---------------- launch ----------------
extern "C" void kernel_launch(void* const* d_in, const int* in_sizes, int n_in,
                              void* d_out, int out_size, void* d_ws, size_t ws_size,
                              hipStream_t stream)
{
  const int*   inputs  = (const int*)d_in[0];
  const int*   lengths = (const int*)d_in[1];
  const int*   targets = (const int*)d_in[2];
  const float* emb     = (const float*)d_in[3];
  const float* Wk_f    = (const float*)d_in[4];
  const float* Wr_f    = (const float*)d_in[5];
  const float* b_f     = (const float*)d_in[6];
  const float* Wk_b    = (const float*)d_in[7];
  const float* Wr_b    = (const float*)d_in[8];
  const float* b_b     = (const float*)d_in[9];
  const float* dense_W = (const float*)d_in[10];
  const float* dense_b = (const float*)d_in[11];
  const float* trans   = (const float*)d_in[12];

  char* ws = (char*)d_ws;
  u16*         wkt    = (u16*)ws;                              //  1,310,720 B
  signed char* wr8    = (signed char*)(ws + 1310720ull);       //    524,288 B
  u16*         embf16 = (u16*)(ws + 1835008ull);               // 19,200,000 B
  u16*         xz     = (u16*)(ws + 1835008ull + 19200000ull); // 134,217,728 B
  u16*         hcat   = (u16*)(ws + 1835008ull + 19200000ull + 134217728ull); // 33,554,432 B

  float* out_logits = (float*)d_out;
  float* out_ll     = out_logits + (size_t)BATCH * TSEQ * NCLS;
  float* out_trans  = out_ll + BATCH;

  hipLaunchKernelGGL(embcvt_k, dim3(1875), dim3(256), 0, stream, emb, embf16);
  hipLaunchKernelGGL(wkt_k, dim3(64, 2), dim3(256), 0, stream, Wk_f, Wk_b, wkt);
  hipLaunchKernelGGL(wr8_k, dim3(64, 2), dim3(256), 0, stream, Wr_f, Wr_b, wr8);
  hipLaunchKernelGGL(xz_gemm_k, dim3(16, 256), dim3(256), 0, stream,
                     inputs, wkt, embf16, b_f, b_b, xz);
  hipLaunchKernelGGL(lstm_k, dim3(128), dim3(512), 0, stream,
                     xz, wr8, lengths, hcat);
  hipLaunchKernelGGL(dense_k, dim3(1024), dim3(256), 0, stream,
                     hcat, dense_W, dense_b, out_logits);
  hipLaunchKernelGGL(crf_k, dim3(64), dim3(64), 0, stream,
                     out_logits, targets, lengths, trans, out_ll, out_trans);
}